// Round 13
// baseline (409.653 us; speedup 1.0000x reference)
//
#include <hip/hip_runtime.h>

#define F 256
#define TNB 16
#define SLOPE 0.01f

typedef __attribute__((ext_vector_type(8))) short short8;
typedef __attribute__((ext_vector_type(4))) short short4v;
typedef __attribute__((ext_vector_type(4))) float f32x4;

__device__ __forceinline__ short f2b(float f) {
    unsigned u = __builtin_bit_cast(unsigned, f);
    u = (u + 0x7FFFu + ((u >> 16) & 1u)) >> 16;   // RNE
    return (short)u;
}
__device__ __forceinline__ float b2f(short s) {
    return __builtin_bit_cast(float, ((unsigned)(unsigned short)s) << 16);
}
__device__ __forceinline__ void gld_lds16(const void* g, void* l) {
    __builtin_amdgcn_global_load_lds((const __attribute__((address_space(1))) void*)g,
                                     (__attribute__((address_space(3))) void*)l, 16, 0, 0);
}

// ---------------------------------------------------------------------------
__global__ void init_map_kernel(int* __restrict__ map, int n) {
    int i = blockIdx.x * blockDim.x + threadIdx.x;
    if (i < n) map[i] = -1;
}
__global__ void build_map_kernel(int* __restrict__ map, const int* __restrict__ nodeset, int n) {
    int i = blockIdx.x * blockDim.x + threadIdx.x;
    if (i < n) atomicMax(&map[nodeset[i]], i);
}
__global__ void cvt_bf16_kernel(const float* __restrict__ src, short* __restrict__ dst, int n) {
    int i = blockIdx.x * blockDim.x + threadIdx.x;
    if (i < n) dst[i] = f2b(src[i]);
}

// ---------------------------------------------------------------------------
// qh_kernel v9: qh = bf16(leaky(Q0 h + b)), h read ONCE (fp32). M=32 tile.
// Block = 256 thr / 4 waves, 2 blocks/CU. Wave's B-slice pinned in 128 VGPRs.
// A staged via global_load_lds into 2x32KB LDS dbuf, src-granule XOR swizzle.
// 2-phase loop: stage(next) -> compute(cur) -> barrier.
// ---------------------------------------------------------------------------
__global__ __launch_bounds__(256, 2) void qh_kernel(
    const float* __restrict__ h,
    const float* __restrict__ Qw, const float* __restrict__ Qb,
    short* __restrict__ qh, int NTILES)   // NTILES = NN/32
{
    __shared__ __align__(16) float Abuf[2][32][256];   // 2 x 32 KB fp32, swizzled

    const int lane = threadIdx.x & 63;
    const int wave = threadIdx.x >> 6;
    const int brow = lane & 15;
    const int kgrp = lane >> 4;
    const int slice = wave;                 // wave owns cols slice*64 .. +63

    // ---- pin wave's B slice: 32 frags = 128 VGPRs (cvt fp32 -> bf16) ----
    short8 bq[8][4];
    #pragma unroll
    for (int kk = 0; kk < 8; ++kk)
        #pragma unroll
        for (int ni = 0; ni < 4; ++ni) {
            const float* bp = Qw + ((size_t)(slice * 64 + ni * 16 + brow)) * 256
                                 + kk * 32 + kgrp * 8;
            float4 u0 = *(const float4*)(bp);
            float4 u1 = *(const float4*)(bp + 4);
            short8 s;
            s[0] = f2b(u0.x); s[1] = f2b(u0.y); s[2] = f2b(u0.z); s[3] = f2b(u0.w);
            s[4] = f2b(u1.x); s[5] = f2b(u1.y); s[6] = f2b(u1.z); s[7] = f2b(u1.w);
            bq[kk][ni] = s;
        }
    float qb[4];
    #pragma unroll
    for (int ni = 0; ni < 4; ++ni) qb[ni] = Qb[slice * 64 + ni * 16 + brow];
    asm volatile("" ::: "memory");          // bq no longer rematerializable

    // stage tile t into buf b: 32 rows, wave stages rows wave*8..+7 (1 glds/row)
    auto stage = [&](int b, int t) {
        #pragma unroll
        for (int i = 0; i < 8; ++i) {
            int r = wave * 8 + i;
            const char* src = (const char*)(h + (((size_t)(t * 32 + r)) << 8))
                              + (((lane & ~7) | ((lane ^ r) & 7)) << 4);
            gld_lds16(src, (char*)&Abuf[b][r][0]);   // HW: dest + lane*16
        }
    };

    int t = blockIdx.x;
    const int stride = gridDim.x;
    if (t >= NTILES) return;

    stage(0, t);
    __syncthreads();
    int cur = 0;

    while (t < NTILES) {
        const int tn = t + stride;
        if (tn < NTILES) stage(cur ^ 1, tn);   // fire-and-forget prefetch

        // ---- compute tile t: M=32, N=64 (slice), K=256 ----
        f32x4 acc[2][4];
        #pragma unroll
        for (int mi = 0; mi < 2; ++mi)
            #pragma unroll
            for (int ni = 0; ni < 4; ++ni) acc[mi][ni] = (f32x4)0.f;

        #pragma unroll
        for (int kk = 0; kk < 8; ++kk) {
            const int g0 = kk * 8 + kgrp * 2;
            const int g1 = g0 + 1;
            #pragma unroll
            for (int mi = 0; mi < 2; ++mi) {
                const int row = mi * 16 + brow;
                const float* rowp = &Abuf[cur][row][0];
                float4 u0 = *(const float4*)(rowp + (((g0 & ~7) | ((g0 ^ row) & 7)) << 2));
                float4 u1 = *(const float4*)(rowp + (((g1 & ~7) | ((g1 ^ row) & 7)) << 2));
                short8 a;
                a[0] = f2b(u0.x); a[1] = f2b(u0.y); a[2] = f2b(u0.z); a[3] = f2b(u0.w);
                a[4] = f2b(u1.x); a[5] = f2b(u1.y); a[6] = f2b(u1.z); a[7] = f2b(u1.w);
                #pragma unroll
                for (int ni = 0; ni < 4; ++ni)
                    acc[mi][ni] = __builtin_amdgcn_mfma_f32_16x16x32_bf16(a, bq[kk][ni], acc[mi][ni], 0, 0, 0);
            }
        }

        // ---- epilogue: bias + leaky -> qh. D: row=mi*16+kgrp*4+r, col=ni*16+brow ----
        #pragma unroll
        for (int mi = 0; mi < 2; ++mi) {
            const int row0 = t * 32 + mi * 16 + kgrp * 4;
            #pragma unroll
            for (int ni = 0; ni < 4; ++ni) {
                #pragma unroll
                for (int r = 0; r < 4; ++r) {
                    float v = acc[mi][ni][r] + qb[ni];
                    v = fmaxf(v, SLOPE * v);
                    qh[(((size_t)(row0 + r)) << 8) + slice * 64 + ni * 16 + brow] = f2b(v);
                }
            }
        }

        __syncthreads();    // drains prefetch; Abuf[cur^1] ready
        cur ^= 1;
        t = tn;
    }
}

// ---------------------------------------------------------------------------
// w0_kernel (agg FUSED): per node, weighted mean of 16 qh rows computed
// in-register (identical rounding to the old agg kernel: fp32 sum -> f2b),
// written straight into Acat LDS; then W-GEMM + normalize. M-tile=32/block.
// ---------------------------------------------------------------------------
__global__ __launch_bounds__(256, 4) void w0_kernel(
    const float* __restrict__ h, const short* __restrict__ qh,
    const int* __restrict__ nodeset,
    const int* __restrict__ nb_nodes, const float* __restrict__ nb_w,
    const short* __restrict__ Wwb, const float* __restrict__ Wb,
    short* __restrict__ new0)
{
    __shared__ __align__(16) short Acat[32][512];
    __shared__ float nsq_sh[32];

    const int tid  = threadIdx.x;
    const int wave = tid >> 6;
    const int lane = tid & 63;
    const int brow = lane & 15;
    const int kgrp = lane >> 4;
    const int base = blockIdx.x * 32;

    if (tid < 32) nsq_sh[tid] = 0.f;

    float wb[4];
    #pragma unroll
    for (int ni = 0; ni < 4; ++ni) wb[ni] = Wb[wave * 64 + ni * 16 + brow];

    #pragma unroll
    for (int i = 0; i < 8; ++i) {
        int r = wave * 8 + i;
        int node = base + r;

        // ---- self row: fp32 h -> bf16 ----
        int g = nodeset[node];
        float4 vf = *((const float4*)(h + ((size_t)g << 8)) + lane);
        short4v s; s.x = f2b(vf.x); s.y = f2b(vf.y); s.z = f2b(vf.z); s.w = f2b(vf.w);

        // ---- fused agg: weighted mean of 16 qh rows (fp32 accum) ----
        int idx  = nb_nodes[node * 16 + (lane & 15)];
        float wt = nb_w[node * 16 + (lane & 15)];
        float denom = wt;
        #pragma unroll
        for (int m = 1; m < 16; m <<= 1) denom += __shfl_xor(denom, m, 64);
        if (denom == 0.f) denom = 1.f;
        const float inv_d = 1.0f / denom;

        float a0 = 0.f, a1 = 0.f, a2 = 0.f, a3 = 0.f;
        #pragma unroll
        for (int t = 0; t < 16; ++t) {
            int gg = __shfl(idx, t, 64);
            float w = __shfl(wt, t, 64);
            short4v v = *((const short4v*)(qh + ((size_t)gg << 8)) + lane);
            a0 = fmaf(w, b2f(v.x), a0);
            a1 = fmaf(w, b2f(v.y), a1);
            a2 = fmaf(w, b2f(v.z), a2);
            a3 = fmaf(w, b2f(v.w), a3);
        }
        short4v o;
        o.x = f2b(a0 * inv_d); o.y = f2b(a1 * inv_d);
        o.z = f2b(a2 * inv_d); o.w = f2b(a3 * inv_d);

        // ---- write [self | agg] into Acat, swizzled granules ----
        int gx = lane >> 1;
        char* rb = (char*)&Acat[0][0] + r * 1024;
        *(short4v*)(rb + (((gx & ~7) | ((gx ^ r) & 7)) << 4) + ((lane & 1) << 3)) = s;
        int gx2 = 32 + gx;
        *(short4v*)(rb + (((gx2 & ~7) | ((gx2 ^ r) & 7)) << 4) + ((lane & 1) << 3)) = o;
    }
    __syncthreads();

    f32x4 acc[2][4];
    #pragma unroll
    for (int mi = 0; mi < 2; ++mi)
        #pragma unroll
        for (int ni = 0; ni < 4; ++ni) acc[mi][ni] = (f32x4)0.f;

    #pragma unroll
    for (int kk = 0; kk < 16; ++kk) {
        const int gx = kk * 4 + kgrp;
        short8 a[2];
        #pragma unroll
        for (int mi = 0; mi < 2; ++mi) {
            int arow = mi * 16 + brow;
            a[mi] = *(const short8*)((const char*)&Acat[0][0] + arow * 1024 +
                                     (((gx & ~7) | ((gx ^ arow) & 7)) << 4));
        }
        #pragma unroll
        for (int ni = 0; ni < 4; ++ni) {
            short8 b = *(const short8*)(
                Wwb + (((size_t)(wave * 64 + ni * 16 + brow)) << 9) + kk * 32 + kgrp * 8);
            #pragma unroll
            for (int mi = 0; mi < 2; ++mi)
                acc[mi][ni] = __builtin_amdgcn_mfma_f32_16x16x32_bf16(a[mi], b, acc[mi][ni], 0, 0, 0);
        }
    }

    float vv[2][4][4];
    float ps[2][4];
    #pragma unroll
    for (int mi = 0; mi < 2; ++mi)
        #pragma unroll
        for (int r = 0; r < 4; ++r) ps[mi][r] = 0.f;
    #pragma unroll
    for (int mi = 0; mi < 2; ++mi)
        #pragma unroll
        for (int ni = 0; ni < 4; ++ni)
            #pragma unroll
            for (int r = 0; r < 4; ++r) {
                float v = acc[mi][ni][r] + wb[ni];
                v = fmaxf(v, SLOPE * v);
                vv[mi][ni][r] = v;
                ps[mi][r] = fmaf(v, v, ps[mi][r]);
            }
    #pragma unroll
    for (int m = 1; m < 16; m <<= 1)
        #pragma unroll
        for (int mi = 0; mi < 2; ++mi)
            #pragma unroll
            for (int r = 0; r < 4; ++r) ps[mi][r] += __shfl_xor(ps[mi][r], m, 64);
    if (brow == 0) {
        #pragma unroll
        for (int mi = 0; mi < 2; ++mi)
            #pragma unroll
            for (int r = 0; r < 4; ++r)
                atomicAdd(&nsq_sh[mi * 16 + kgrp * 4 + r], ps[mi][r]);
    }
    __syncthreads();

    #pragma unroll
    for (int mi = 0; mi < 2; ++mi)
        #pragma unroll
        for (int r = 0; r < 4; ++r) {
            int row = mi * 16 + kgrp * 4 + r;
            float nrm = sqrtf(nsq_sh[row]);
            if (nrm == 0.f) nrm = 1.f;
            float inv_n = 1.0f / nrm;
            #pragma unroll
            for (int ni = 0; ni < 4; ++ni)
                new0[((size_t)(base + row) << 8) + wave * 64 + ni * 16 + brow] =
                    f2b(vv[mi][ni][r] * inv_n);
        }
}

// ---------------------------------------------------------------------------
// Layer-1 fused conv. Sources: map0-redirect -> new0 (bf16) else h (fp32->bf16).
// ---------------------------------------------------------------------------
__device__ __forceinline__ short8 load_row16(const float* __restrict__ h,
                                             const short* __restrict__ new0,
                                             const int* __restrict__ map0,
                                             int g, int gx) {   // gx = 16B granule in bf16 row
    int m = map0[g];
    if (m >= 0)
        return *(const short8*)((const char*)new0 + (((size_t)m) << 9) + (gx << 4));
    const float* p = h + (((size_t)g) << 8) + gx * 8;
    float4 u0 = *(const float4*)p;
    float4 u1 = *(const float4*)(p + 4);
    short8 s;
    s[0] = f2b(u0.x); s[1] = f2b(u0.y); s[2] = f2b(u0.z); s[3] = f2b(u0.w);
    s[4] = f2b(u1.x); s[5] = f2b(u1.y); s[6] = f2b(u1.z); s[7] = f2b(u1.w);
    return s;
}

__global__ __launch_bounds__(256, 2) void conv_mfma_kernel(
    const float* __restrict__ h, const short* __restrict__ new0,
    const int* __restrict__ map0,
    const int* __restrict__ nodeset, const int* __restrict__ nb_nodes,
    const float* __restrict__ nb_w,
    const short* __restrict__ Qwb, const float* __restrict__ Qb,
    const short* __restrict__ Wwb, const float* __restrict__ Wb,
    float* __restrict__ out)
{
    __shared__ __align__(16) short Abuf[2][32][256];
    __shared__ __align__(16) short Hself[16][256];
    __shared__ __align__(16) short Hagg[16][264];
    __shared__ float wsh[16][16];
    __shared__ float nsq_sh[16];

    const int tid  = threadIdx.x;
    const int wave = tid >> 6;
    const int lane = tid & 63;
    const int brow = lane & 15;
    const int kgrp = lane >> 4;
    const int nb_base = blockIdx.x * 16;

    wsh[tid >> 4][tid & 15] = nb_w[nb_base * TNB + tid];
    if (tid < 16) nsq_sh[tid] = 0.f;

    float qb[4], wb[4];
    #pragma unroll
    for (int ni = 0; ni < 4; ++ni) {
        qb[ni] = Qb[wave * 64 + ni * 16 + brow];
        wb[ni] = Wb[wave * 64 + ni * 16 + brow];
    }

    const int rl = wave * 8 + (lane >> 3);
    const int sb = lane & 7;
    auto rowgid = [&](int rnd) {
        int nl = rnd * 2 + (rl >> 4);
        return nb_nodes[(nb_base + nl) * TNB + (rl & 15)];
    };

    {
        const int rl2  = wave * 4 + (lane >> 4);
        const int slot = lane & 15;
        int gs = nodeset[nb_base + rl2];
        short8 s0 = load_row16(h, new0, map0, gs, slot);
        short8 s1 = load_row16(h, new0, map0, gs, slot + 16);
        char* dstS = (char*)&Hself[0][0] + rl2 * 512 + ((slot ^ (rl2 & 7)) << 4);
        *(short8*)(dstS)       = s0;
        *(short8*)(dstS + 256) = s1;
    }
    {
        int gA = rowgid(0);
        short8 v0 = load_row16(h, new0, map0, gA, sb);
        short8 v1 = load_row16(h, new0, map0, gA, sb + 8);
        short8 v2 = load_row16(h, new0, map0, gA, sb + 16);
        short8 v3 = load_row16(h, new0, map0, gA, sb + 24);
        char* dstA = (char*)&Abuf[0][0][0] + rl * 512 + ((sb ^ (rl & 7)) << 4);
        *(short8*)(dstA)       = v0;
        *(short8*)(dstA + 128) = v1;
        *(short8*)(dstA + 256) = v2;
        *(short8*)(dstA + 384) = v3;
    }
    int gCur = rowgid(1);

    short8 bq[8][4];
    #pragma unroll
    for (int kk = 0; kk < 8; ++kk)
        #pragma unroll
        for (int ni = 0; ni < 4; ++ni)
            bq[kk][ni] = *(const short8*)(
                Qwb + (((size_t)(wave * 64 + ni * 16 + brow)) << 8) + kk * 32 + kgrp * 8);

    __syncthreads();

    #pragma unroll
    for (int rnd = 0; rnd < 8; ++rnd) {
        const int b = rnd & 1;
        int gNext = 0;
        if (rnd < 6) gNext = rowgid(rnd + 2);
        short8 w0, w1, w2, w3;
        if (rnd < 7) {
            w0 = load_row16(h, new0, map0, gCur, sb);
            w1 = load_row16(h, new0, map0, gCur, sb + 8);
            w2 = load_row16(h, new0, map0, gCur, sb + 16);
            w3 = load_row16(h, new0, map0, gCur, sb + 24);
        }

        const char* ab = (const char*)&Abuf[b][0][0];
        f32x4 acc[2][4];
        #pragma unroll
        for (int mi = 0; mi < 2; ++mi)
            #pragma unroll
            for (int ni = 0; ni < 4; ++ni) acc[mi][ni] = (f32x4)0.f;

        #pragma unroll
        for (int kk = 0; kk < 8; ++kk) {
            const int sx = ((kk * 4 + kgrp) ^ (brow & 7)) << 4;
            short8 a0 = *(const short8*)(ab + brow * 512 + sx);
            short8 a1 = *(const short8*)(ab + (16 + brow) * 512 + sx);
            #pragma unroll
            for (int ni = 0; ni < 4; ++ni) {
                acc[0][ni] = __builtin_amdgcn_mfma_f32_16x16x32_bf16(a0, bq[kk][ni], acc[0][ni], 0, 0, 0);
                acc[1][ni] = __builtin_amdgcn_mfma_f32_16x16x32_bf16(a1, bq[kk][ni], acc[1][ni], 0, 0, 0);
            }
        }

        #pragma unroll
        for (int mi = 0; mi < 2; ++mi) {
            const int nl = rnd * 2 + mi;
            float denom = 0.f;
            #pragma unroll
            for (int t = 0; t < TNB; ++t) denom += wsh[nl][t];
            if (denom == 0.f) denom = 1.f;
            float inv_d = 1.0f / denom;
            float w4[4];
            #pragma unroll
            for (int r = 0; r < 4; ++r) w4[r] = wsh[nl][kgrp * 4 + r];
            #pragma unroll
            for (int ni = 0; ni < 4; ++ni) {
                float pacc = 0.f;
                #pragma unroll
                for (int r = 0; r < 4; ++r) {
                    float v = acc[mi][ni][r] + qb[ni];
                    v = fmaxf(v, SLOPE * v);
                    pacc = fmaf(w4[r], v, pacc);
                }
                pacc += __shfl_xor(pacc, 16, 64);
                pacc += __shfl_xor(pacc, 32, 64);
                if (kgrp == 0) Hagg[nl][wave * 64 + ni * 16 + brow] = f2b(pacc * inv_d);
            }
        }

        if (rnd < 7) {
            char* dstA = (char*)&Abuf[b ^ 1][0][0] + rl * 512 + ((sb ^ (rl & 7)) << 4);
            *(short8*)(dstA)       = w0;
            *(short8*)(dstA + 128) = w1;
            *(short8*)(dstA + 256) = w2;
            *(short8*)(dstA + 384) = w3;
            gCur = gNext;
        }
        __syncthreads();
    }

    f32x4 acc2[4];
    #pragma unroll
    for (int ni = 0; ni < 4; ++ni) acc2[ni] = (f32x4)0.f;

    #pragma unroll
    for (int kk = 0; kk < 8; ++kk) {
        const int sx = ((kk * 4 + kgrp) ^ (brow & 7)) << 4;
        short8 a = *(const short8*)((const char*)&Hself[0][0] + brow * 512 + sx);
        #pragma unroll
        for (int ni = 0; ni < 4; ++ni) {
            short8 bb = *(const short8*)(
                Wwb + (((size_t)(wave * 64 + ni * 16 + brow)) << 9) + kk * 32 + kgrp * 8);
            acc2[ni] = __builtin_amdgcn_mfma_f32_16x16x32_bf16(a, bb, acc2[ni], 0, 0, 0);
        }
    }
    #pragma unroll
    for (int kk = 0; kk < 8; ++kk) {
        short8 a = *(const short8*)(&Hagg[brow][kk * 32 + kgrp * 8]);
        #pragma unroll
        for (int ni = 0; ni < 4; ++ni) {
            short8 bb = *(const short8*)(
                Wwb + (((size_t)(wave * 64 + ni * 16 + brow)) << 9) + 256 + kk * 32 + kgrp * 8);
            acc2[ni] = __builtin_amdgcn_mfma_f32_16x16x32_bf16(a, bb, acc2[ni], 0, 0, 0);
        }
    }

    float vv[4][4];
    float ps[4] = {0.f, 0.f, 0.f, 0.f};
    #pragma unroll
    for (int ni = 0; ni < 4; ++ni)
        #pragma unroll
        for (int r = 0; r < 4; ++r) {
            float v = acc2[ni][r] + wb[ni];
            v = fmaxf(v, SLOPE * v);
            vv[ni][r] = v;
            ps[r] = fmaf(v, v, ps[r]);
        }
    #pragma unroll
    for (int m = 1; m < 16; m <<= 1)
        #pragma unroll
        for (int r = 0; r < 4; ++r) ps[r] += __shfl_xor(ps[r], m, 64);
    if (brow == 0) {
        #pragma unroll
        for (int r = 0; r < 4; ++r) atomicAdd(&nsq_sh[kgrp * 4 + r], ps[r]);
    }
    __syncthreads();

    #pragma unroll
    for (int r = 0; r < 4; ++r) {
        int node = kgrp * 4 + r;
        float nrm = sqrtf(nsq_sh[node]);
        if (nrm == 0.f) nrm = 1.f;
        float inv_n = 1.0f / nrm;
        #pragma unroll
        for (int ni = 0; ni < 4; ++ni)
            out[(size_t)(nb_base + node) * F + wave * 64 + ni * 16 + brow] = vv[ni][r] * inv_n;
    }
}

__global__ void gather_out_kernel(float* __restrict__ out, const float* __restrict__ new1,
                                  const int* __restrict__ map1, const int* __restrict__ nodeset1) {
    int i = blockIdx.x;
    int f = threadIdx.x;
    int w = map1[nodeset1[i]];
    out[(size_t)i * F + f] = new1[(size_t)w * F + f];
}

extern "C" void kernel_launch(void* const* d_in, const int* in_sizes, int n_in,
                              void* d_out, int out_size, void* d_ws, size_t ws_size,
                              hipStream_t stream) {
    const float* h    = (const float*)d_in[0];
    const float* Q0w  = (const float*)d_in[1];
    const float* Q0b  = (const float*)d_in[2];
    const float* W0w  = (const float*)d_in[3];
    const float* W0b  = (const float*)d_in[4];
    const float* Q1w  = (const float*)d_in[5];
    const float* Q1b  = (const float*)d_in[6];
    const float* W1w  = (const float*)d_in[7];
    const float* W1b  = (const float*)d_in[8];
    const float* nbw0 = (const float*)d_in[9];
    const float* nbw1 = (const float*)d_in[10];
    const int* ns0    = (const int*)d_in[11];
    const int* nbn0   = (const int*)d_in[12];
    const int* ns1    = (const int*)d_in[13];
    const int* nbn1   = (const int*)d_in[14];

    const int L0 = in_sizes[11];        // 65536
    const int L1 = in_sizes[13];        // 4096
    const int NN = in_sizes[0] / F;     // 500000

    char* ws = (char*)d_ws;
    short* qh   = (short*)ws; ws += (size_t)NN * F * sizeof(short);   // 256 MB
    short* new0 = (short*)ws; ws += (size_t)L0 * F * sizeof(short);   // 32 MB (separate: w0 reads qh while writing new0)
    float* new1 = (float*)ws; ws += (size_t)L1 * F * sizeof(float);   // 4 MB
    int* map0 = (int*)ws;     ws += (size_t)NN * sizeof(int);
    int* map1 = (int*)ws;     ws += (size_t)NN * sizeof(int);
    short* W0wb = (short*)ws; ws += (size_t)F * 2 * F * sizeof(short);
    short* Q1wb = (short*)ws; ws += (size_t)F * F * sizeof(short);
    short* W1wb = (short*)ws;

    cvt_bf16_kernel<<<(F * 2 * F + 255) / 256, 256, 0, stream>>>(W0w, W0wb, F * 2 * F);
    cvt_bf16_kernel<<<(F * F + 255) / 256, 256, 0, stream>>>(Q1w, Q1wb, F * F);
    cvt_bf16_kernel<<<(F * 2 * F + 255) / 256, 256, 0, stream>>>(W1w, W1wb, F * 2 * F);
    init_map_kernel<<<(NN + 255) / 256, 256, 0, stream>>>(map0, NN);
    init_map_kernel<<<(NN + 255) / 256, 256, 0, stream>>>(map1, NN);
    build_map_kernel<<<(L0 + 255) / 256, 256, 0, stream>>>(map0, ns0, L0);
    build_map_kernel<<<(L1 + 255) / 256, 256, 0, stream>>>(map1, ns1, L1);

    // layer 0: dense Q pass, then fused agg+W pass
    const int NTILES = NN / 32;         // 15625
    qh_kernel<<<512, 256, 0, stream>>>(h, Q0w, Q0b, qh, NTILES);
    w0_kernel<<<L0 / 32, 256, 0, stream>>>(h, qh, ns0, nbn0, nbw0, W0wb, W0b, new0);

    // layer 1 (reads h + new0 via map0 redirect)
    conv_mfma_kernel<<<L1 / 16, 256, 0, stream>>>(
        h, new0, map0, ns1, nbn1, nbw1, Q1wb, Q1b, W1wb, W1b, new1);
    gather_out_kernel<<<L1, 256, 0, stream>>>((float*)d_out, new1, map1, ns1);
}

// Round 14
// 394.206 us; speedup vs baseline: 1.0392x; 1.0392x over previous
//
#include <hip/hip_runtime.h>

#define F 256
#define TNB 16
#define SLOPE 0.01f

typedef __attribute__((ext_vector_type(8))) short short8;
typedef __attribute__((ext_vector_type(4))) short short4v;
typedef __attribute__((ext_vector_type(4))) float f32x4;

__device__ __forceinline__ short f2b(float f) {
    unsigned u = __builtin_bit_cast(unsigned, f);
    u = (u + 0x7FFFu + ((u >> 16) & 1u)) >> 16;   // RNE
    return (short)u;
}
__device__ __forceinline__ float b2f(short s) {
    return __builtin_bit_cast(float, ((unsigned)(unsigned short)s) << 16);
}
__device__ __forceinline__ void gld_lds16(const void* g, void* l) {
    __builtin_amdgcn_global_load_lds((const __attribute__((address_space(1))) void*)g,
                                     (__attribute__((address_space(3))) void*)l, 16, 0, 0);
}

// ---------------------------------------------------------------------------
// consolidated prep: one init over both maps, one build over both nodesets,
// one cvt over all three weight matrices (contiguous dst).
// ---------------------------------------------------------------------------
__global__ void init_maps_kernel(int* __restrict__ maps, int n2) {
    int i = blockIdx.x * blockDim.x + threadIdx.x;
    if (i < n2) maps[i] = -1;
}
__global__ void build_maps_kernel(int* __restrict__ map0, const int* __restrict__ ns0, int L0,
                                  int* __restrict__ map1, const int* __restrict__ ns1, int L1) {
    int i = blockIdx.x * blockDim.x + threadIdx.x;
    if (i < L0) atomicMax(&map0[ns0[i]], i);
    else if (i < L0 + L1) { int j = i - L0; atomicMax(&map1[ns1[j]], j); }
}
__global__ void cvt_weights_kernel(const float* __restrict__ W0w, const float* __restrict__ Q1w,
                                   const float* __restrict__ W1w, short* __restrict__ dst) {
    int i = blockIdx.x * blockDim.x + threadIdx.x;      // 0 .. 5*F*F-1
    const int FF = F * F;
    float v;
    if (i < 2 * FF)          v = W0w[i];
    else if (i < 3 * FF)     v = Q1w[i - 2 * FF];
    else if (i < 5 * FF)     v = W1w[i - 3 * FF];
    else return;
    dst[i] = f2b(v);
}

// ---------------------------------------------------------------------------
// qh_kernel (r12-proven): qh = bf16(leaky(Q0 h + b)), h read ONCE (fp32).
// Block = 256 thr / 4 waves, 2 blocks/CU. Wave's B-slice pinned in 128 VGPRs.
// A staged via global_load_lds into 2x16KB LDS dbuf, src-granule XOR swizzle.
// ---------------------------------------------------------------------------
__global__ __launch_bounds__(256, 2) void qh_kernel(
    const float* __restrict__ h,
    const float* __restrict__ Qw, const float* __restrict__ Qb,
    short* __restrict__ qh, int NTILES)
{
    __shared__ __align__(16) float Abuf[2][16][256];   // 2 x 16 KB fp32, swizzled

    const int lane = threadIdx.x & 63;
    const int wave = threadIdx.x >> 6;
    const int brow = lane & 15;
    const int kgrp = lane >> 4;
    const int slice = wave;

    short8 bq[8][4];
    #pragma unroll
    for (int kk = 0; kk < 8; ++kk)
        #pragma unroll
        for (int ni = 0; ni < 4; ++ni) {
            const float* bp = Qw + ((size_t)(slice * 64 + ni * 16 + brow)) * 256
                                 + kk * 32 + kgrp * 8;
            float4 u0 = *(const float4*)(bp);
            float4 u1 = *(const float4*)(bp + 4);
            short8 s;
            s[0] = f2b(u0.x); s[1] = f2b(u0.y); s[2] = f2b(u0.z); s[3] = f2b(u0.w);
            s[4] = f2b(u1.x); s[5] = f2b(u1.y); s[6] = f2b(u1.z); s[7] = f2b(u1.w);
            bq[kk][ni] = s;
        }
    float qb[4];
    #pragma unroll
    for (int ni = 0; ni < 4; ++ni) qb[ni] = Qb[slice * 64 + ni * 16 + brow];
    asm volatile("" ::: "memory");

    auto stage = [&](int b, int t) {
        #pragma unroll
        for (int i = 0; i < 4; ++i) {
            int r = wave * 4 + i;
            const char* src = (const char*)(h + (((size_t)(t * 16 + r)) << 8))
                              + (((lane & ~7) | ((lane ^ r) & 7)) << 4);
            gld_lds16(src, (char*)&Abuf[b][r][0]);
        }
    };

    int t = blockIdx.x;
    const int stride = gridDim.x;
    if (t >= NTILES) return;

    stage(0, t);
    __syncthreads();
    int cur = 0;

    while (t < NTILES) {
        const int tn = t + stride;
        if (tn < NTILES) stage(cur ^ 1, tn);

        f32x4 acc[4];
        #pragma unroll
        for (int ni = 0; ni < 4; ++ni) acc[ni] = (f32x4)0.f;

        #pragma unroll
        for (int kk = 0; kk < 8; ++kk) {
            const int g0 = kk * 8 + kgrp * 2;
            const int g1 = g0 + 1;
            const float* rowp = &Abuf[cur][brow][0];
            float4 u0 = *(const float4*)(rowp + (((g0 & ~7) | ((g0 ^ brow) & 7)) << 2));
            float4 u1 = *(const float4*)(rowp + (((g1 & ~7) | ((g1 ^ brow) & 7)) << 2));
            short8 a;
            a[0] = f2b(u0.x); a[1] = f2b(u0.y); a[2] = f2b(u0.z); a[3] = f2b(u0.w);
            a[4] = f2b(u1.x); a[5] = f2b(u1.y); a[6] = f2b(u1.z); a[7] = f2b(u1.w);
            #pragma unroll
            for (int ni = 0; ni < 4; ++ni)
                acc[ni] = __builtin_amdgcn_mfma_f32_16x16x32_bf16(a, bq[kk][ni], acc[ni], 0, 0, 0);
        }

        const int row0 = t * 16 + kgrp * 4;
        #pragma unroll
        for (int ni = 0; ni < 4; ++ni) {
            #pragma unroll
            for (int r = 0; r < 4; ++r) {
                float v = acc[ni][r] + qb[ni];
                v = fmaxf(v, SLOPE * v);
                qh[(((size_t)(row0 + r)) << 8) + slice * 64 + ni * 16 + brow] = f2b(v);
            }
        }

        __syncthreads();
        cur ^= 1;
        t = tn;
    }
}

// ---------------------------------------------------------------------------
// agg_kernel: per node, weighted mean of 16 qh rows. 1 node/wave, no LDS/bars.
// ---------------------------------------------------------------------------
__global__ __launch_bounds__(256, 4) void agg_kernel(
    const short* __restrict__ qh, const int* __restrict__ nb_nodes,
    const float* __restrict__ nb_w, short* __restrict__ agg)
{
    const int wave = threadIdx.x >> 6;
    const int lane = threadIdx.x & 63;
    const int n = blockIdx.x * 4 + wave;

    int idx = nb_nodes[n * 16 + (lane & 15)];
    float wt = nb_w[n * 16 + (lane & 15)];
    float denom = wt;
    #pragma unroll
    for (int m = 1; m < 16; m <<= 1) denom += __shfl_xor(denom, m, 64);
    if (denom == 0.f) denom = 1.f;
    const float inv_d = 1.0f / denom;

    float a0 = 0.f, a1 = 0.f, a2 = 0.f, a3 = 0.f;
    #pragma unroll
    for (int t = 0; t < 16; ++t) {
        int g = __shfl(idx, t, 64);
        float w = __shfl(wt, t, 64);
        short4v v = *((const short4v*)(qh + ((size_t)g << 8)) + lane);
        a0 = fmaf(w, b2f(v.x), a0);
        a1 = fmaf(w, b2f(v.y), a1);
        a2 = fmaf(w, b2f(v.z), a2);
        a3 = fmaf(w, b2f(v.w), a3);
    }
    short4v o;
    o.x = f2b(a0 * inv_d); o.y = f2b(a1 * inv_d);
    o.z = f2b(a2 * inv_d); o.w = f2b(a3 * inv_d);
    *((short4v*)(agg + ((size_t)n << 8)) + lane) = o;
}

// ---------------------------------------------------------------------------
// w0_kernel: new0 = bf16(normalize(leaky(W0 [self|agg] + b))). M-tile=32/block.
// ---------------------------------------------------------------------------
__global__ __launch_bounds__(256, 4) void w0_kernel(
    const float* __restrict__ h, const short* __restrict__ agg,
    const int* __restrict__ nodeset,
    const short* __restrict__ Wwb, const float* __restrict__ Wb,
    short* __restrict__ new0)
{
    __shared__ __align__(16) short Acat[32][512];
    __shared__ float nsq_sh[32];

    const int tid  = threadIdx.x;
    const int wave = tid >> 6;
    const int lane = tid & 63;
    const int brow = lane & 15;
    const int kgrp = lane >> 4;
    const int base = blockIdx.x * 32;

    if (tid < 32) nsq_sh[tid] = 0.f;

    float wb[4];
    #pragma unroll
    for (int ni = 0; ni < 4; ++ni) wb[ni] = Wb[wave * 64 + ni * 16 + brow];

    #pragma unroll
    for (int i = 0; i < 8; ++i) {
        int r = wave * 8 + i;
        int node = base + r;
        int g = nodeset[node];
        float4 vf = *((const float4*)(h + ((size_t)g << 8)) + lane);
        short4v s; s.x = f2b(vf.x); s.y = f2b(vf.y); s.z = f2b(vf.z); s.w = f2b(vf.w);
        short4v a = *((const short4v*)(agg + ((size_t)node << 8)) + lane);
        int gx = lane >> 1;
        char* rb = (char*)&Acat[0][0] + r * 1024;
        *(short4v*)(rb + (((gx & ~7) | ((gx ^ r) & 7)) << 4) + ((lane & 1) << 3)) = s;
        int gx2 = 32 + gx;
        *(short4v*)(rb + (((gx2 & ~7) | ((gx2 ^ r) & 7)) << 4) + ((lane & 1) << 3)) = a;
    }
    __syncthreads();

    f32x4 acc[2][4];
    #pragma unroll
    for (int mi = 0; mi < 2; ++mi)
        #pragma unroll
        for (int ni = 0; ni < 4; ++ni) acc[mi][ni] = (f32x4)0.f;

    #pragma unroll
    for (int kk = 0; kk < 16; ++kk) {
        const int gx = kk * 4 + kgrp;
        short8 a[2];
        #pragma unroll
        for (int mi = 0; mi < 2; ++mi) {
            int arow = mi * 16 + brow;
            a[mi] = *(const short8*)((const char*)&Acat[0][0] + arow * 1024 +
                                     (((gx & ~7) | ((gx ^ arow) & 7)) << 4));
        }
        #pragma unroll
        for (int ni = 0; ni < 4; ++ni) {
            short8 b = *(const short8*)(
                Wwb + (((size_t)(wave * 64 + ni * 16 + brow)) << 9) + kk * 32 + kgrp * 8);
            #pragma unroll
            for (int mi = 0; mi < 2; ++mi)
                acc[mi][ni] = __builtin_amdgcn_mfma_f32_16x16x32_bf16(a[mi], b, acc[mi][ni], 0, 0, 0);
        }
    }

    float vv[2][4][4];
    float ps[2][4];
    #pragma unroll
    for (int mi = 0; mi < 2; ++mi)
        #pragma unroll
        for (int r = 0; r < 4; ++r) ps[mi][r] = 0.f;
    #pragma unroll
    for (int mi = 0; mi < 2; ++mi)
        #pragma unroll
        for (int ni = 0; ni < 4; ++ni)
            #pragma unroll
            for (int r = 0; r < 4; ++r) {
                float v = acc[mi][ni][r] + wb[ni];
                v = fmaxf(v, SLOPE * v);
                vv[mi][ni][r] = v;
                ps[mi][r] = fmaf(v, v, ps[mi][r]);
            }
    #pragma unroll
    for (int m = 1; m < 16; m <<= 1)
        #pragma unroll
        for (int mi = 0; mi < 2; ++mi)
            #pragma unroll
            for (int r = 0; r < 4; ++r) ps[mi][r] += __shfl_xor(ps[mi][r], m, 64);
    if (brow == 0) {
        #pragma unroll
        for (int mi = 0; mi < 2; ++mi)
            #pragma unroll
            for (int r = 0; r < 4; ++r)
                atomicAdd(&nsq_sh[mi * 16 + kgrp * 4 + r], ps[mi][r]);
    }
    __syncthreads();

    #pragma unroll
    for (int mi = 0; mi < 2; ++mi)
        #pragma unroll
        for (int r = 0; r < 4; ++r) {
            int row = mi * 16 + kgrp * 4 + r;
            float nrm = sqrtf(nsq_sh[row]);
            if (nrm == 0.f) nrm = 1.f;
            float inv_n = 1.0f / nrm;
            #pragma unroll
            for (int ni = 0; ni < 4; ++ni)
                new0[((size_t)(base + row) << 8) + wave * 64 + ni * 16 + brow] =
                    f2b(vv[mi][ni][r] * inv_n);
        }
}

// ---------------------------------------------------------------------------
// Layer-1 fused conv. Sources: map0-redirect -> new0 (bf16) else h (fp32->bf16).
// ---------------------------------------------------------------------------
__device__ __forceinline__ short8 load_row16(const float* __restrict__ h,
                                             const short* __restrict__ new0,
                                             const int* __restrict__ map0,
                                             int g, int gx) {
    int m = map0[g];
    if (m >= 0)
        return *(const short8*)((const char*)new0 + (((size_t)m) << 9) + (gx << 4));
    const float* p = h + (((size_t)g) << 8) + gx * 8;
    float4 u0 = *(const float4*)p;
    float4 u1 = *(const float4*)(p + 4);
    short8 s;
    s[0] = f2b(u0.x); s[1] = f2b(u0.y); s[2] = f2b(u0.z); s[3] = f2b(u0.w);
    s[4] = f2b(u1.x); s[5] = f2b(u1.y); s[6] = f2b(u1.z); s[7] = f2b(u1.w);
    return s;
}

__global__ __launch_bounds__(256, 2) void conv_mfma_kernel(
    const float* __restrict__ h, const short* __restrict__ new0,
    const int* __restrict__ map0,
    const int* __restrict__ nodeset, const int* __restrict__ nb_nodes,
    const float* __restrict__ nb_w,
    const short* __restrict__ Qwb, const float* __restrict__ Qb,
    const short* __restrict__ Wwb, const float* __restrict__ Wb,
    float* __restrict__ out)
{
    __shared__ __align__(16) short Abuf[2][32][256];
    __shared__ __align__(16) short Hself[16][256];
    __shared__ __align__(16) short Hagg[16][264];
    __shared__ float wsh[16][16];
    __shared__ float nsq_sh[16];

    const int tid  = threadIdx.x;
    const int wave = tid >> 6;
    const int lane = tid & 63;
    const int brow = lane & 15;
    const int kgrp = lane >> 4;
    const int nb_base = blockIdx.x * 16;

    wsh[tid >> 4][tid & 15] = nb_w[nb_base * TNB + tid];
    if (tid < 16) nsq_sh[tid] = 0.f;

    float qb[4], wb[4];
    #pragma unroll
    for (int ni = 0; ni < 4; ++ni) {
        qb[ni] = Qb[wave * 64 + ni * 16 + brow];
        wb[ni] = Wb[wave * 64 + ni * 16 + brow];
    }

    const int rl = wave * 8 + (lane >> 3);
    const int sb = lane & 7;
    auto rowgid = [&](int rnd) {
        int nl = rnd * 2 + (rl >> 4);
        return nb_nodes[(nb_base + nl) * TNB + (rl & 15)];
    };

    {
        const int rl2  = wave * 4 + (lane >> 4);
        const int slot = lane & 15;
        int gs = nodeset[nb_base + rl2];
        short8 s0 = load_row16(h, new0, map0, gs, slot);
        short8 s1 = load_row16(h, new0, map0, gs, slot + 16);
        char* dstS = (char*)&Hself[0][0] + rl2 * 512 + ((slot ^ (rl2 & 7)) << 4);
        *(short8*)(dstS)       = s0;
        *(short8*)(dstS + 256) = s1;
    }
    {
        int gA = rowgid(0);
        short8 v0 = load_row16(h, new0, map0, gA, sb);
        short8 v1 = load_row16(h, new0, map0, gA, sb + 8);
        short8 v2 = load_row16(h, new0, map0, gA, sb + 16);
        short8 v3 = load_row16(h, new0, map0, gA, sb + 24);
        char* dstA = (char*)&Abuf[0][0][0] + rl * 512 + ((sb ^ (rl & 7)) << 4);
        *(short8*)(dstA)       = v0;
        *(short8*)(dstA + 128) = v1;
        *(short8*)(dstA + 256) = v2;
        *(short8*)(dstA + 384) = v3;
    }
    int gCur = rowgid(1);

    short8 bq[8][4];
    #pragma unroll
    for (int kk = 0; kk < 8; ++kk)
        #pragma unroll
        for (int ni = 0; ni < 4; ++ni)
            bq[kk][ni] = *(const short8*)(
                Qwb + (((size_t)(wave * 64 + ni * 16 + brow)) << 8) + kk * 32 + kgrp * 8);

    __syncthreads();

    #pragma unroll
    for (int rnd = 0; rnd < 8; ++rnd) {
        const int b = rnd & 1;
        int gNext = 0;
        if (rnd < 6) gNext = rowgid(rnd + 2);
        short8 w0, w1, w2, w3;
        if (rnd < 7) {
            w0 = load_row16(h, new0, map0, gCur, sb);
            w1 = load_row16(h, new0, map0, gCur, sb + 8);
            w2 = load_row16(h, new0, map0, gCur, sb + 16);
            w3 = load_row16(h, new0, map0, gCur, sb + 24);
        }

        const char* ab = (const char*)&Abuf[b][0][0];
        f32x4 acc[2][4];
        #pragma unroll
        for (int mi = 0; mi < 2; ++mi)
            #pragma unroll
            for (int ni = 0; ni < 4; ++ni) acc[mi][ni] = (f32x4)0.f;

        #pragma unroll
        for (int kk = 0; kk < 8; ++kk) {
            const int sx = ((kk * 4 + kgrp) ^ (brow & 7)) << 4;
            short8 a0 = *(const short8*)(ab + brow * 512 + sx);
            short8 a1 = *(const short8*)(ab + (16 + brow) * 512 + sx);
            #pragma unroll
            for (int ni = 0; ni < 4; ++ni) {
                acc[0][ni] = __builtin_amdgcn_mfma_f32_16x16x32_bf16(a0, bq[kk][ni], acc[0][ni], 0, 0, 0);
                acc[1][ni] = __builtin_amdgcn_mfma_f32_16x16x32_bf16(a1, bq[kk][ni], acc[1][ni], 0, 0, 0);
            }
        }

        #pragma unroll
        for (int mi = 0; mi < 2; ++mi) {
            const int nl = rnd * 2 + mi;
            float denom = 0.f;
            #pragma unroll
            for (int t = 0; t < TNB; ++t) denom += wsh[nl][t];
            if (denom == 0.f) denom = 1.f;
            float inv_d = 1.0f / denom;
            float w4[4];
            #pragma unroll
            for (int r = 0; r < 4; ++r) w4[r] = wsh[nl][kgrp * 4 + r];
            #pragma unroll
            for (int ni = 0; ni < 4; ++ni) {
                float pacc = 0.f;
                #pragma unroll
                for (int r = 0; r < 4; ++r) {
                    float v = acc[mi][ni][r] + qb[ni];
                    v = fmaxf(v, SLOPE * v);
                    pacc = fmaf(w4[r], v, pacc);
                }
                pacc += __shfl_xor(pacc, 16, 64);
                pacc += __shfl_xor(pacc, 32, 64);
                if (kgrp == 0) Hagg[nl][wave * 64 + ni * 16 + brow] = f2b(pacc * inv_d);
            }
        }

        if (rnd < 7) {
            char* dstA = (char*)&Abuf[b ^ 1][0][0] + rl * 512 + ((sb ^ (rl & 7)) << 4);
            *(short8*)(dstA)       = w0;
            *(short8*)(dstA + 128) = w1;
            *(short8*)(dstA + 256) = w2;
            *(short8*)(dstA + 384) = w3;
            gCur = gNext;
        }
        __syncthreads();
    }

    f32x4 acc2[4];
    #pragma unroll
    for (int ni = 0; ni < 4; ++ni) acc2[ni] = (f32x4)0.f;

    #pragma unroll
    for (int kk = 0; kk < 8; ++kk) {
        const int sx = ((kk * 4 + kgrp) ^ (brow & 7)) << 4;
        short8 a = *(const short8*)((const char*)&Hself[0][0] + brow * 512 + sx);
        #pragma unroll
        for (int ni = 0; ni < 4; ++ni) {
            short8 bb = *(const short8*)(
                Wwb + (((size_t)(wave * 64 + ni * 16 + brow)) << 9) + kk * 32 + kgrp * 8);
            acc2[ni] = __builtin_amdgcn_mfma_f32_16x16x32_bf16(a, bb, acc2[ni], 0, 0, 0);
        }
    }
    #pragma unroll
    for (int kk = 0; kk < 8; ++kk) {
        short8 a = *(const short8*)(&Hagg[brow][kk * 32 + kgrp * 8]);
        #pragma unroll
        for (int ni = 0; ni < 4; ++ni) {
            short8 bb = *(const short8*)(
                Wwb + (((size_t)(wave * 64 + ni * 16 + brow)) << 9) + 256 + kk * 32 + kgrp * 8);
            acc2[ni] = __builtin_amdgcn_mfma_f32_16x16x32_bf16(a, bb, acc2[ni], 0, 0, 0);
        }
    }

    float vv[4][4];
    float ps[4] = {0.f, 0.f, 0.f, 0.f};
    #pragma unroll
    for (int ni = 0; ni < 4; ++ni)
        #pragma unroll
        for (int r = 0; r < 4; ++r) {
            float v = acc2[ni][r] + wb[ni];
            v = fmaxf(v, SLOPE * v);
            vv[ni][r] = v;
            ps[r] = fmaf(v, v, ps[r]);
        }
    #pragma unroll
    for (int m = 1; m < 16; m <<= 1)
        #pragma unroll
        for (int r = 0; r < 4; ++r) ps[r] += __shfl_xor(ps[r], m, 64);
    if (brow == 0) {
        #pragma unroll
        for (int r = 0; r < 4; ++r) atomicAdd(&nsq_sh[kgrp * 4 + r], ps[r]);
    }
    __syncthreads();

    #pragma unroll
    for (int r = 0; r < 4; ++r) {
        int node = kgrp * 4 + r;
        float nrm = sqrtf(nsq_sh[node]);
        if (nrm == 0.f) nrm = 1.f;
        float inv_n = 1.0f / nrm;
        #pragma unroll
        for (int ni = 0; ni < 4; ++ni)
            out[(size_t)(nb_base + node) * F + wave * 64 + ni * 16 + brow] = vv[ni][r] * inv_n;
    }
}

__global__ void gather_out_kernel(float* __restrict__ out, const float* __restrict__ new1,
                                  const int* __restrict__ map1, const int* __restrict__ nodeset1) {
    int i = blockIdx.x;
    int f = threadIdx.x;
    int w = map1[nodeset1[i]];
    out[(size_t)i * F + f] = new1[(size_t)w * F + f];
}

extern "C" void kernel_launch(void* const* d_in, const int* in_sizes, int n_in,
                              void* d_out, int out_size, void* d_ws, size_t ws_size,
                              hipStream_t stream) {
    const float* h    = (const float*)d_in[0];
    const float* Q0w  = (const float*)d_in[1];
    const float* Q0b  = (const float*)d_in[2];
    const float* W0w  = (const float*)d_in[3];
    const float* W0b  = (const float*)d_in[4];
    const float* Q1w  = (const float*)d_in[5];
    const float* Q1b  = (const float*)d_in[6];
    const float* W1w  = (const float*)d_in[7];
    const float* W1b  = (const float*)d_in[8];
    const float* nbw0 = (const float*)d_in[9];
    const float* nbw1 = (const float*)d_in[10];
    const int* ns0    = (const int*)d_in[11];
    const int* nbn0   = (const int*)d_in[12];
    const int* ns1    = (const int*)d_in[13];
    const int* nbn1   = (const int*)d_in[14];

    const int L0 = in_sizes[11];        // 65536
    const int L1 = in_sizes[13];        // 4096
    const int NN = in_sizes[0] / F;     // 500000

    char* ws = (char*)d_ws;
    short* qh   = (short*)ws; ws += (size_t)NN * F * sizeof(short);   // 256 MB (dead after agg)
    short* agg  = (short*)ws; ws += (size_t)L0 * F * sizeof(short);   // 32 MB
    int* maps = (int*)ws;     ws += (size_t)2 * NN * sizeof(int);     // map0 | map1 contiguous
    int* map0 = maps;
    int* map1 = maps + NN;
    short* wblk = (short*)ws; ws += (size_t)5 * F * F * sizeof(short); // W0wb|Q1wb|W1wb contiguous
    short* W0wb = wblk;
    short* Q1wb = wblk + 2 * F * F;
    short* W1wb = wblk + 3 * F * F;
    // alias the dead qh region after agg completes:
    short* new0 = qh;                                        // 32 MB bf16
    float* new1 = (float*)((char*)qh + ((size_t)48 << 20));  // 4 MB fp32

    cvt_weights_kernel<<<(5 * F * F + 255) / 256, 256, 0, stream>>>(W0w, Q1w, W1w, wblk);
    init_maps_kernel<<<(2 * NN + 255) / 256, 256, 0, stream>>>(maps, 2 * NN);
    build_maps_kernel<<<(L0 + L1 + 255) / 256, 256, 0, stream>>>(map0, ns0, L0, map1, ns1, L1);

    // layer 0
    const int NTILES = NN / 16;         // 31250
    qh_kernel<<<512, 256, 0, stream>>>(h, Q0w, Q0b, qh, NTILES);
    agg_kernel<<<L0 / 4, 256, 0, stream>>>(qh, nbn0, nbw0, agg);
    w0_kernel<<<L0 / 32, 256, 0, stream>>>(h, agg, ns0, W0wb, W0b, new0);

    // layer 1 (reads h + new0 via map0 redirect)
    conv_mfma_kernel<<<L1 / 16, 256, 0, stream>>>(
        h, new0, map0, ns1, nbn1, nbw1, Q1wb, Q1b, W1wb, W1b, new1);
    gather_out_kernel<<<L1, 256, 0, stream>>>((float*)d_out, new1, map1, ns1);
}